// Round 2
// 1010.871 us; speedup vs baseline: 1.2349x; 1.2349x over previous
//
#include <hip/hip_runtime.h>
#include <math.h>

#define NROWS 524288
#define CHUNK 16
#define NCHUNK (NROWS / CHUNK)   // 32768
#define GRID 4096                // 8 chunks per block

typedef _Float16 half2_t __attribute__((ext_vector_type(2)));

__device__ __forceinline__ float gelu_exact(float x) {
    // jax.nn.gelu(approximate=False) = 0.5*x*(1+erf(x/sqrt(2)))
    return 0.5f * x * (1.0f + erff(x * 0.70710678118654752440f));
}

// Packed-pair dot with fp32 accumulate. Primary: v_dot2_f32_f16 (2 MACs/inst).
// Fallback (if builtin missing on this toolchain): unpack + fmaf — keeps the
// packed-register layout (the spill fix) and only loses the 2x issue rate.
__device__ __forceinline__ float dot2_acc(half2_t a, half2_t b, float acc) {
#if __has_builtin(__builtin_amdgcn_fdot2)
    return __builtin_amdgcn_fdot2(a, b, acc, false);
#else
    acc = fmaf((float)a[0], (float)b[0], acc);
    acc = fmaf((float)a[1], (float)b[1], acc);
    return acc;
#endif
}

__global__ __launch_bounds__(256, 4)
void encoder_kernel(const int* __restrict__ read_count,
                    const int* __restrict__ write_count,
                    const int* __restrict__ fault_count,
                    const int* __restrict__ cow_count,
                    const int* __restrict__ recency,
                    const float* __restrict__ volatility,
                    const float* __restrict__ pressure,
                    const float* __restrict__ count_emb,
                    const float* __restrict__ recency_emb,
                    const float* __restrict__ p_w1, const float* __restrict__ p_b1,
                    const float* __restrict__ p_w2, const float* __restrict__ p_b2,
                    const float* __restrict__ v_w1, const float* __restrict__ v_b1,
                    const float* __restrict__ v_w2, const float* __restrict__ v_b2,
                    const float* __restrict__ f_wh, const float* __restrict__ f_bh,
                    const float* __restrict__ f_wg, const float* __restrict__ f_bg,
                    const float* __restrict__ ln_g, const float* __restrict__ ln_b,
                    float* __restrict__ out)
{
    __shared__ __align__(16) float s_cemb[320];
    __shared__ __align__(16) float s_remb[320];
    __shared__ __align__(16) float s_vw1[32];
    __shared__ __align__(16) float s_vw2[48];
    __shared__ __align__(16) float s_pw1[288];
    __shared__ __align__(16) float s_pw2[480];
    __shared__ float s_vb1[8], s_vb2[8], s_pb1[24], s_pb2[20];
    __shared__ __align__(16) float s_hid[CHUNK][32];
    // combined[51] packed as f16 pairs: 26 data dwords + 2 zero-pad dwords = 28
    // row stride 112 B (16B-aligned) so each row reads as 7x ds_read_b128.
    __shared__ __align__(16) half2_t s_comb[CHUNK][28];
    __shared__ __align__(16) float s_z[CHUNK][256];
    __shared__ float s_mu[CHUNK], s_rs[CHUNK];

    const int tid  = threadIdx.x;
    const int lane = tid & 63;
    const int wave = tid >> 6;

    // ---- param staging (once per block) ----
    for (int i = tid; i < 320; i += 256) { s_cemb[i] = count_emb[i]; s_remb[i] = recency_emb[i]; }
    if (tid < 8)  s_vb1[tid] = v_b1[tid];
    if (tid < 6)  s_vb2[tid] = v_b2[tid];
    if (tid < 24) s_pb1[tid] = p_b1[tid];
    if (tid < 20) s_pb2[tid] = p_b2[tid];
    // zero the 2 pad dwords of every s_comb row once; they stay zero across chunks
    if (tid < CHUNK * 2) {
        half2_t z; z[0] = (_Float16)0.0f; z[1] = (_Float16)0.0f;
        s_comb[tid >> 1][26 + (tid & 1)] = z;
    }

    // ---- BitNet ternary quantization, one tensor per wave ----
    {
        const float* src; float* dst; int n;
        if (wave == 0)      { src = v_w1; dst = s_vw1; n = 32;  }
        else if (wave == 1) { src = v_w2; dst = s_vw2; n = 48;  }
        else if (wave == 2) { src = p_w1; dst = s_pw1; n = 288; }
        else                { src = p_w2; dst = s_pw2; n = 480; }
        float s = 0.0f;
        for (int i = lane; i < n; i += 64) s += fabsf(src[i]);
        #pragma unroll
        for (int off = 32; off > 0; off >>= 1) s += __shfl_xor(s, off, 64);
        const float scale = s / (float)n;       // per-tensor absmean
        const float den   = scale + 1e-5f;
        for (int i = lane; i < n; i += 64) {
            float q = rintf(src[i] / den);      // rintf = round-half-even (matches jnp.round)
            q = fminf(1.0f, fmaxf(-1.0f, q));
            dst[i] = q * scale;
        }
    }

    // ---- per-thread fused-projection weights, packed f16 pairs ----
    // 28+28 dwords instead of 102 fp32 regs: fits the RF, no spill, and the
    // dot runs as v_dot2_f32_f16 (2 MACs/inst, fp32 accumulate).
    half2_t wh[28], wg[28];
    #pragma unroll
    for (int j = 0; j < 28; ++j) {
        const int k0 = 2 * j, k1 = 2 * j + 1;
        float h0 = (k0 < 51) ? f_wh[tid * 51 + k0] : 0.0f;
        float h1 = (k1 < 51) ? f_wh[tid * 51 + k1] : 0.0f;
        float g0 = (k0 < 51) ? f_wg[tid * 51 + k0] : 0.0f;
        float g1 = (k1 < 51) ? f_wg[tid * 51 + k1] : 0.0f;
        wh[j][0] = (_Float16)h0; wh[j][1] = (_Float16)h1;
        wg[j][0] = (_Float16)g0; wg[j][1] = (_Float16)g1;
    }
    const float bh = f_bh[tid], bg = f_bg[tid];
    const float lgam = ln_g[tid], lbet = ln_b[tid];
    __syncthreads();

    for (int c = blockIdx.x; c < NCHUNK; c += GRID) {
        const long long row0 = (long long)c * CHUNK;

        // Phase A: hidden neurons for both MLPs (16 rows x 32 units)
        for (int t2 = tid; t2 < CHUNK * 32; t2 += 256) {
            const int r = t2 >> 5, u = t2 & 31;
            const long long R = row0 + r;
            float acc;
            if (u < 24) {
                acc = s_pb1[u];
                const float* w = s_pw1 + u * 12;
                const float* x = pressure + R * 12;
                #pragma unroll
                for (int k = 0; k < 12; ++k) acc = fmaf(w[k], x[k], acc);
            } else {
                const int uu = u - 24;
                acc = s_vb1[uu];
                const float* w = s_vw1 + uu * 4;
                const float* x = volatility + R * 4;
                #pragma unroll
                for (int k = 0; k < 4; ++k) acc = fmaf(w[k], x[k], acc);
            }
            s_hid[r][u] = gelu_exact(acc);
        }
        __syncthreads();

        // Phase B: assemble combined[51] per row as packed f16 pairs
        // (emb 0..24 | p_vol 25..30 | p_pres 31..50 | 51 = zero)
        for (int t2 = tid; t2 < CHUNK * 26; t2 += 256) {
            const int r = t2 / 26, p = t2 - r * 26;
            const long long R = row0 + r;
            auto cval = [&](int sIdx) -> float {
                if (sIdx < 25) {
                    const int table = sIdx / 5, pos = sIdx - table * 5;
                    int idx; const float* emb = s_cemb;
                    switch (table) {
                        case 0: idx = read_count[R];  break;
                        case 1: idx = write_count[R]; break;
                        case 2: idx = fault_count[R]; break;
                        case 3: idx = cow_count[R];   break;
                        default: idx = recency[R]; emb = s_remb; break;
                    }
                    return emb[idx * 5 + pos];
                } else if (sIdx < 31) {
                    const int u = sIdx - 25;
                    float acc = s_vb2[u];
                    #pragma unroll
                    for (int k = 0; k < 8; ++k) acc = fmaf(s_vw2[u * 8 + k], s_hid[r][24 + k], acc);
                    return acc;
                } else if (sIdx < 51) {
                    const int u = sIdx - 31;
                    float acc = s_pb2[u];
                    #pragma unroll
                    for (int k = 0; k < 24; ++k) acc = fmaf(s_pw2[u * 24 + k], s_hid[r][k], acc);
                    return acc;
                }
                return 0.0f;
            };
            const float v0 = cval(2 * p);
            const float v1 = cval(2 * p + 1);
            half2_t pk; pk[0] = (_Float16)v0; pk[1] = (_Float16)v1;
            s_comb[r][p] = pk;
        }
        __syncthreads();

        // Phase C: fused 51->512 projection; thread owns (h[tid], g[tid]).
        // 7x ds_read_b128 broadcast + 56 packed dots per row.
        #pragma unroll 1
        for (int r = 0; r < CHUNK; ++r) {
            float ah0 = 0.0f, ah1 = 0.0f, ag0 = 0.0f, ag1 = 0.0f;
            const uint4* crow = reinterpret_cast<const uint4*>(&s_comb[r][0]);
            #pragma unroll
            for (int q = 0; q < 7; ++q) {
                const uint4 cv = crow[q];
                const half2_t c0 = __builtin_bit_cast(half2_t, cv.x);
                const half2_t c1 = __builtin_bit_cast(half2_t, cv.y);
                const half2_t c2 = __builtin_bit_cast(half2_t, cv.z);
                const half2_t c3 = __builtin_bit_cast(half2_t, cv.w);
                ah0 = dot2_acc(c0, wh[4 * q + 0], ah0);
                ag0 = dot2_acc(c0, wg[4 * q + 0], ag0);
                ah1 = dot2_acc(c1, wh[4 * q + 1], ah1);
                ag1 = dot2_acc(c1, wg[4 * q + 1], ag1);
                ah0 = dot2_acc(c2, wh[4 * q + 2], ah0);
                ag0 = dot2_acc(c2, wg[4 * q + 2], ag0);
                ah1 = dot2_acc(c3, wh[4 * q + 3], ah1);
                ag1 = dot2_acc(c3, wg[4 * q + 3], ag1);
            }
            const float hv = (ah0 + ah1) + bh;
            const float gv = 1.0f / (1.0f + __expf(-((ag0 + ag1) + bg)));
            s_z[r][tid] = gv * hv;
        }
        __syncthreads();

        // Phase D: LayerNorm stats, 16 lanes per row; XOR column phase by row
        // so the 4 rows of a wave hit 2 bank sets (2-way = free) not 4-way.
        {
            const int r = tid >> 4, l = tid & 15;
            float sum = 0.0f, sq = 0.0f;
            #pragma unroll
            for (int j = 0; j < 16; ++j) {
                const int col = l + 16 * ((j + r) & 15);
                const float z = s_z[r][col];
                sum += z; sq += z * z;
            }
            #pragma unroll
            for (int off = 1; off < 16; off <<= 1) {
                sum += __shfl_xor(sum, off, 64);
                sq  += __shfl_xor(sq,  off, 64);
            }
            const float mu  = sum * (1.0f / 256.0f);
            const float var = sq * (1.0f / 256.0f) - mu * mu;
            if (l == 0) { s_mu[r] = mu; s_rs[r] = rsqrtf(var + 1e-5f); }
        }
        __syncthreads();

        // Phase E: normalize + coalesced nontemporal store
        #pragma unroll 1
        for (int r = 0; r < CHUNK; ++r) {
            const float val = (s_z[r][tid] - s_mu[r]) * s_rs[r] * lgam + lbet;
            __builtin_nontemporal_store(val, &out[(row0 + r) * 256 + tid]);
        }
        __syncthreads();
    }
}

extern "C" void kernel_launch(void* const* d_in, const int* in_sizes, int n_in,
                              void* d_out, int out_size, void* d_ws, size_t ws_size,
                              hipStream_t stream) {
    const int*   read_count  = (const int*)d_in[0];
    const int*   write_count = (const int*)d_in[1];
    const int*   fault_count = (const int*)d_in[2];
    const int*   cow_count   = (const int*)d_in[3];
    const int*   recency     = (const int*)d_in[4];
    const float* volatility  = (const float*)d_in[5];
    const float* pressure    = (const float*)d_in[6];
    const float* count_emb   = (const float*)d_in[7];
    const float* recency_emb = (const float*)d_in[8];
    const float* p_w1 = (const float*)d_in[9];
    const float* p_b1 = (const float*)d_in[10];
    const float* p_w2 = (const float*)d_in[11];
    const float* p_b2 = (const float*)d_in[12];
    const float* v_w1 = (const float*)d_in[13];
    const float* v_b1 = (const float*)d_in[14];
    const float* v_w2 = (const float*)d_in[15];
    const float* v_b2 = (const float*)d_in[16];
    const float* f_wh = (const float*)d_in[17];
    const float* f_bh = (const float*)d_in[18];
    const float* f_wg = (const float*)d_in[19];
    const float* f_bg = (const float*)d_in[20];
    const float* ln_g = (const float*)d_in[21];
    const float* ln_b = (const float*)d_in[22];
    float* out = (float*)d_out;

    encoder_kernel<<<GRID, 256, 0, stream>>>(
        read_count, write_count, fault_count, cow_count, recency,
        volatility, pressure, count_emb, recency_emb,
        p_w1, p_b1, p_w2, p_b2, v_w1, v_b1, v_w2, v_b2,
        f_wh, f_bh, f_wg, f_bg, ln_g, ln_b, out);
}

// Round 3
// 942.799 us; speedup vs baseline: 1.3240x; 1.0722x over previous
//
#include <hip/hip_runtime.h>
#include <math.h>

#define NROWS 524288
#define CHUNK 16
#define NCHUNK (NROWS / CHUNK)   // 32768
#define GRID 4096                // 8 chunks per block

typedef _Float16 half2_t __attribute__((ext_vector_type(2)));
typedef _Float16 f16x8  __attribute__((ext_vector_type(8)));
typedef float    f32x4  __attribute__((ext_vector_type(4)));

__device__ __forceinline__ float gelu_exact(float x) {
    // jax.nn.gelu(approximate=False) = 0.5*x*(1+erf(x/sqrt(2)))
    return 0.5f * x * (1.0f + erff(x * 0.70710678118654752440f));
}

// s_comb row stride in dwords (72 f16 = 36 dwords = 144 B).
// Stride 36 staggers rows by 4 banks: fragment b128 reads spread evenly
// (8 lanes per bank-quad = the b128 minimum), vs 16-way at stride 32.
#define CSTRIDE 36

__global__ __launch_bounds__(256, 3)
void encoder_kernel(const int* __restrict__ read_count,
                    const int* __restrict__ write_count,
                    const int* __restrict__ fault_count,
                    const int* __restrict__ cow_count,
                    const int* __restrict__ recency,
                    const float* __restrict__ volatility,
                    const float* __restrict__ pressure,
                    const float* __restrict__ count_emb,
                    const float* __restrict__ recency_emb,
                    const float* __restrict__ p_w1, const float* __restrict__ p_b1,
                    const float* __restrict__ p_w2, const float* __restrict__ p_b2,
                    const float* __restrict__ v_w1, const float* __restrict__ v_b1,
                    const float* __restrict__ v_w2, const float* __restrict__ v_b2,
                    const float* __restrict__ f_wh, const float* __restrict__ f_bh,
                    const float* __restrict__ f_wg, const float* __restrict__ f_bg,
                    const float* __restrict__ ln_g, const float* __restrict__ ln_b,
                    float* __restrict__ out)
{
    __shared__ __align__(16) float s_cemb[320];
    __shared__ __align__(16) float s_remb[320];
    __shared__ __align__(16) float s_vw1[32];
    __shared__ __align__(16) float s_vw2[48];
    __shared__ __align__(16) float s_pw1[288];
    __shared__ __align__(16) float s_pw2[480];
    __shared__ float s_vb1[8], s_vb2[8], s_pb1[24], s_pb2[20];
    __shared__ __align__(16) float s_hid[CHUNK][32];
    // combined[51] as f16, K padded to 64 (k=51..63 zero), + 8 f16 stride pad
    __shared__ __align__(16) unsigned int s_combd[CHUNK * CSTRIDE];
    __shared__ __align__(16) float s_z[CHUNK][256];
    __shared__ float s_mu[CHUNK], s_rs[CHUNK];

    const int tid  = threadIdx.x;
    const int lane = tid & 63;
    const int wave = tid >> 6;

    // ---- param staging (once per block) ----
    for (int i = tid; i < 320; i += 256) { s_cemb[i] = count_emb[i]; s_remb[i] = recency_emb[i]; }
    if (tid < 8)  s_vb1[tid] = v_b1[tid];
    if (tid < 6)  s_vb2[tid] = v_b2[tid];
    if (tid < 24) s_pb1[tid] = p_b1[tid];
    if (tid < 20) s_pb2[tid] = p_b2[tid];

    // ---- BitNet ternary quantization, one tensor per wave ----
    {
        const float* src; float* dst; int n;
        if (wave == 0)      { src = v_w1; dst = s_vw1; n = 32;  }
        else if (wave == 1) { src = v_w2; dst = s_vw2; n = 48;  }
        else if (wave == 2) { src = p_w1; dst = s_pw1; n = 288; }
        else                { src = p_w2; dst = s_pw2; n = 480; }
        float s = 0.0f;
        for (int i = lane; i < n; i += 64) s += fabsf(src[i]);
        #pragma unroll
        for (int off = 32; off > 0; off >>= 1) s += __shfl_xor(s, off, 64);
        const float scale = s / (float)n;       // per-tensor absmean
        const float den   = scale + 1e-5f;
        for (int i = lane; i < n; i += 64) {
            float q = rintf(src[i] / den);      // rintf = round-half-even (matches jnp.round)
            q = fminf(1.0f, fmaxf(-1.0f, q));
            dst[i] = q * scale;
        }
    }

    // ---- B-fragment preload: this wave owns output cols [wave*64, wave*64+64) ----
    // MFMA slot convention (chosen identically for A and B, so the contraction
    // is correct under any consistent HW k-map): lane l slot j -> k = ks*32 + (l>>4)*8 + j.
    // B operand: col = l&15 (+16*t), k as above. k >= 51 zero-padded.
    const int gI = lane >> 4;   // k-group 0..3
    const int cI = lane & 15;   // col-in-tile
    f16x8 bfh[4][2], bfg[4][2];
    float bh_t[4], bg_t[4];
    #pragma unroll
    for (int t = 0; t < 4; ++t) {
        const int n = wave * 64 + t * 16 + cI;
        bh_t[t] = f_bh[n];
        bg_t[t] = f_bg[n];
        #pragma unroll
        for (int ks = 0; ks < 2; ++ks) {
            f16x8 vh, vg;
            #pragma unroll
            for (int j = 0; j < 8; ++j) {
                const int k = ks * 32 + gI * 8 + j;
                const float whv = (k < 51) ? f_wh[n * 51 + k] : 0.0f;
                const float wgv = (k < 51) ? f_wg[n * 51 + k] : 0.0f;
                vh[j] = (_Float16)whv;
                vg[j] = (_Float16)wgv;
            }
            bfh[t][ks] = vh;
            bfg[t][ks] = vg;
        }
    }
    const float lgam = ln_g[tid], lbet = ln_b[tid];
    __syncthreads();

    for (int c = blockIdx.x; c < NCHUNK; c += GRID) {
        const long long row0 = (long long)c * CHUNK;

        // Phase A: hidden neurons for both MLPs (16 rows x 32 units)
        for (int t2 = tid; t2 < CHUNK * 32; t2 += 256) {
            const int r = t2 >> 5, u = t2 & 31;
            const long long R = row0 + r;
            float acc;
            if (u < 24) {
                acc = s_pb1[u];
                const float* w = s_pw1 + u * 12;
                const float* x = pressure + R * 12;
                #pragma unroll
                for (int k = 0; k < 12; ++k) acc = fmaf(w[k], x[k], acc);
            } else {
                const int uu = u - 24;
                acc = s_vb1[uu];
                const float* w = s_vw1 + uu * 4;
                const float* x = volatility + R * 4;
                #pragma unroll
                for (int k = 0; k < 4; ++k) acc = fmaf(w[k], x[k], acc);
            }
            s_hid[r][u] = gelu_exact(acc);
        }
        __syncthreads();

        // Phase B: assemble combined[64] per row as f16 pairs (k=51..63 zero)
        // (emb 0..24 | p_vol 25..30 | p_pres 31..50 | 51.. = 0)
        for (int t2 = tid; t2 < CHUNK * 32; t2 += 256) {
            const int r = t2 >> 5, p = t2 & 31;
            const long long R = row0 + r;
            auto cval = [&](int sIdx) -> float {
                if (sIdx < 25) {
                    const int table = sIdx / 5, pos = sIdx - table * 5;
                    int idx; const float* emb = s_cemb;
                    switch (table) {
                        case 0: idx = read_count[R];  break;
                        case 1: idx = write_count[R]; break;
                        case 2: idx = fault_count[R]; break;
                        case 3: idx = cow_count[R];   break;
                        default: idx = recency[R]; emb = s_remb; break;
                    }
                    return emb[idx * 5 + pos];
                } else if (sIdx < 31) {
                    const int u = sIdx - 25;
                    float acc = s_vb2[u];
                    #pragma unroll
                    for (int k = 0; k < 8; ++k) acc = fmaf(s_vw2[u * 8 + k], s_hid[r][24 + k], acc);
                    return acc;
                } else if (sIdx < 51) {
                    const int u = sIdx - 31;
                    float acc = s_pb2[u];
                    #pragma unroll
                    for (int k = 0; k < 24; ++k) acc = fmaf(s_pw2[u * 24 + k], s_hid[r][k], acc);
                    return acc;
                }
                return 0.0f;
            };
            const float v0 = cval(2 * p);
            const float v1 = cval(2 * p + 1);
            half2_t pk; pk[0] = (_Float16)v0; pk[1] = (_Float16)v1;
            s_combd[r * CSTRIDE + p] = __builtin_bit_cast(unsigned int, pk);
        }
        __syncthreads();

        // Phase C: MFMA 16x16x32_f16, fp32 accumulate.
        // A: lane l holds row = l&15, slots k = ks*32 + (l>>4)*8 + j  (matches B pack).
        // C/D: row = (l>>4)*4 + reg, col = l&15  [verified layout].
        {
            const uint4 a0 = *(const uint4*)(s_combd + cI * CSTRIDE + gI * 4);
            const uint4 a1 = *(const uint4*)(s_combd + cI * CSTRIDE + 16 + gI * 4);
            const f16x8 af0 = __builtin_bit_cast(f16x8, a0);
            const f16x8 af1 = __builtin_bit_cast(f16x8, a1);
            #pragma unroll
            for (int t = 0; t < 4; ++t) {
                f32x4 ach = {0.0f, 0.0f, 0.0f, 0.0f};
                f32x4 acg = {0.0f, 0.0f, 0.0f, 0.0f};
                ach = __builtin_amdgcn_mfma_f32_16x16x32_f16(af0, bfh[t][0], ach, 0, 0, 0);
                ach = __builtin_amdgcn_mfma_f32_16x16x32_f16(af1, bfh[t][1], ach, 0, 0, 0);
                acg = __builtin_amdgcn_mfma_f32_16x16x32_f16(af0, bfg[t][0], acg, 0, 0, 0);
                acg = __builtin_amdgcn_mfma_f32_16x16x32_f16(af1, bfg[t][1], acg, 0, 0, 0);
                const int colo = wave * 64 + t * 16 + cI;
                #pragma unroll
                for (int i = 0; i < 4; ++i) {
                    const float hv = ach[i] + bh_t[t];
                    const float gv = 1.0f / (1.0f + __expf(-(acg[i] + bg_t[t])));
                    s_z[gI * 4 + i][colo] = gv * hv;   // gating in-register, scatter to LDS
                }
            }
        }
        __syncthreads();

        // Phase D: LayerNorm stats, 16 lanes per row; XOR column phase by row
        {
            const int r = tid >> 4, l = tid & 15;
            float sum = 0.0f, sq = 0.0f;
            #pragma unroll
            for (int j = 0; j < 16; ++j) {
                const int col = l + 16 * ((j + r) & 15);
                const float z = s_z[r][col];
                sum += z; sq += z * z;
            }
            #pragma unroll
            for (int off = 1; off < 16; off <<= 1) {
                sum += __shfl_xor(sum, off, 64);
                sq  += __shfl_xor(sq,  off, 64);
            }
            const float mu  = sum * (1.0f / 256.0f);
            const float var = sq * (1.0f / 256.0f) - mu * mu;
            if (l == 0) { s_mu[r] = mu; s_rs[r] = rsqrtf(var + 1e-5f); }
        }
        __syncthreads();

        // Phase E: normalize + coalesced nontemporal store.
        // (No trailing barrier: s_z/s_mu are next written in phase C/D of the
        // next chunk, which is behind the post-A and post-B barriers.)
        #pragma unroll 1
        for (int r = 0; r < CHUNK; ++r) {
            const float val = (s_z[r][tid] - s_mu[r]) * s_rs[r] * lgam + lbet;
            __builtin_nontemporal_store(val, &out[(row0 + r) * 256 + tid]);
        }
    }
}

extern "C" void kernel_launch(void* const* d_in, const int* in_sizes, int n_in,
                              void* d_out, int out_size, void* d_ws, size_t ws_size,
                              hipStream_t stream) {
    const int*   read_count  = (const int*)d_in[0];
    const int*   write_count = (const int*)d_in[1];
    const int*   fault_count = (const int*)d_in[2];
    const int*   cow_count   = (const int*)d_in[3];
    const int*   recency     = (const int*)d_in[4];
    const float* volatility  = (const float*)d_in[5];
    const float* pressure    = (const float*)d_in[6];
    const float* count_emb   = (const float*)d_in[7];
    const float* recency_emb = (const float*)d_in[8];
    const float* p_w1 = (const float*)d_in[9];
    const float* p_b1 = (const float*)d_in[10];
    const float* p_w2 = (const float*)d_in[11];
    const float* p_b2 = (const float*)d_in[12];
    const float* v_w1 = (const float*)d_in[13];
    const float* v_b1 = (const float*)d_in[14];
    const float* v_w2 = (const float*)d_in[15];
    const float* v_b2 = (const float*)d_in[16];
    const float* f_wh = (const float*)d_in[17];
    const float* f_bh = (const float*)d_in[18];
    const float* f_wg = (const float*)d_in[19];
    const float* f_bg = (const float*)d_in[20];
    const float* ln_g = (const float*)d_in[21];
    const float* ln_b = (const float*)d_in[22];
    float* out = (float*)d_out;

    encoder_kernel<<<GRID, 256, 0, stream>>>(
        read_count, write_count, fault_count, cow_count, recency,
        volatility, pressure, count_emb, recency_emb,
        p_w1, p_b1, p_w2, p_b2, v_w1, v_b1, v_w2, v_b2,
        f_wh, f_bh, f_wg, f_bg, ln_g, ln_b, out);
}